// Round 6
// baseline (223.947 us; speedup 1.0000x reference)
//
#include <hip/hip_runtime.h>
#include <hip/hip_bf16.h>

namespace {

constexpr int B = 4, S = 2048, D = 1024, H = 16, DH = 64;
constexpr int KVS = 4;  // kv splits per q-tile (= waves per attn block)

typedef __attribute__((ext_vector_type(8))) short short8;
typedef __attribute__((ext_vector_type(4))) short short4v;
typedef __attribute__((ext_vector_type(2))) unsigned uint2v;
typedef __attribute__((ext_vector_type(4))) float f32x4;
typedef __attribute__((ext_vector_type(16))) float f32x16;

union U8 { unsigned u[4]; short8 s; };
union BF2 { __hip_bfloat162 h; unsigned u; };

__device__ __forceinline__ short f2bf(float f) {
  unsigned u = __builtin_bit_cast(unsigned, f);
  u = (u + 0x7fffu + ((u >> 16) & 1u)) >> 16;
  return (short)u;
}

__device__ __forceinline__ float bf2f(short s) {
  unsigned u = ((unsigned)(unsigned short)s) << 16;
  return __builtin_bit_cast(float, u);
}

// packed f32x2 -> bf16x2 via HIP intrinsic (compiler emits v_cvt_pk_bf16_f32)
__device__ __forceinline__ unsigned pkrn(float a, float b) {
  BF2 r;
  r.h = __float22bfloat162_rn(float2{a, b});
  return r.u;
}

__device__ __forceinline__ float max3f(float a, float b, float c) {
  return fmaxf(fmaxf(a, b), c);
}

__device__ __forceinline__ short8 cvt8(const float* p) {
  float4 a = *reinterpret_cast<const float4*>(p);
  float4 b2 = *reinterpret_cast<const float4*>(p + 4);
  short8 r;
  r[0] = f2bf(a.x); r[1] = f2bf(a.y); r[2] = f2bf(a.z); r[3] = f2bf(a.w);
  r[4] = f2bf(b2.x); r[5] = f2bf(b2.y); r[6] = f2bf(b2.z); r[7] = f2bf(b2.w);
  return r;
}

__device__ __forceinline__ void gl_lds16(const void* g, void* l) {
  __builtin_amdgcn_global_load_lds(
      (const __attribute__((address_space(1))) void*)g,
      (__attribute__((address_space(3))) void*)l, 16, 0, 0);
}

// ---------------------------------------------------------------------------
// Transpose + bf16-convert the 4 weight matrices: WT[n][k] = bf16(W[k][n]).
// ---------------------------------------------------------------------------
__global__ __launch_bounds__(256) void k_transpose(
    const float* __restrict__ Wq, const float* __restrict__ Wk,
    const float* __restrict__ Wv, const float* __restrict__ Wo,
    short* __restrict__ WqT, short* __restrict__ WkT,
    short* __restrict__ WvT, short* __restrict__ WoT) {
  __shared__ float tile[32][33];
  int z = blockIdx.z;
  const float* W = z == 0 ? Wq : z == 1 ? Wk : z == 2 ? Wv : Wo;
  short* WT = z == 0 ? WqT : z == 1 ? WkT : z == 2 ? WvT : WoT;
  int n0 = blockIdx.x * 32, k0 = blockIdx.y * 32;
  int tx = threadIdx.x, ty = threadIdx.y;
#pragma unroll
  for (int i = 0; i < 4; ++i) {
    int r = i * 8 + ty;
    tile[r][tx] = W[(size_t)(k0 + r) * D + n0 + tx];
  }
  __syncthreads();
#pragma unroll
  for (int i = 0; i < 4; ++i) {
    int r = i * 8 + ty;
    WT[(size_t)(n0 + r) * D + k0 + tx] = f2bf(tile[tx][r]);
  }
}

// ---------------------------------------------------------------------------
// Convert x / prev rows of active batches to bf16 (grid: (S*D/2048, 2, B))
// ---------------------------------------------------------------------------
__global__ __launch_bounds__(256) void k_cvt(
    const float* __restrict__ x, const float* __restrict__ prev,
    const int* __restrict__ mask,
    short* __restrict__ xbf, short* __restrict__ pbf) {
  int b = blockIdx.z;
  if (mask[b] == 0) return;
  const float* src = (blockIdx.y ? prev : x) + (size_t)b * S * D;
  short* dst = (blockIdx.y ? pbf : xbf) + (size_t)b * S * D;
  size_t i = ((size_t)blockIdx.x * 256 + threadIdx.x) * 8;
  *reinterpret_cast<short8*>(dst + i) = cvt8(src + i);
}

// ---------------------------------------------------------------------------
// Shared GEMM mainloop (m97 structure): C[128x128] = A[128xK] @ B^T.
// ---------------------------------------------------------------------------
__device__ __forceinline__ void stage128x64(const short* __restrict__ src,
                                            short* lds, int wave, int lane) {
#pragma unroll
  for (int c = 0; c < 4; ++c) {
    int r0 = wave * 32 + c * 8;
    gl_lds16(src + (size_t)(r0 + (lane >> 3)) * D + (lane & 7) * 8,
             lds + r0 * 64);
  }
}

__device__ __forceinline__ void gemm_mainloop(
    const short* __restrict__ A, const short* __restrict__ Bm,
    int m0, int n0, short* ldsA, short* ldsB, f32x4 acc[4][4]) {
  int wave = threadIdx.x >> 6, lane = threadIdx.x & 63;
  int wm = wave >> 1, wn = wave & 1;
  int kg = (lane >> 4) * 8, r = lane & 15;
  const short* Ab = A + (size_t)m0 * D;
  const short* Bb = Bm + (size_t)n0 * D;
  for (int kt = 0; kt < D; kt += 64) {
    stage128x64(Ab + kt, ldsA, wave, lane);
    stage128x64(Bb + kt, ldsB, wave, lane);
    __syncthreads();
#pragma unroll
    for (int kk = 0; kk < 64; kk += 32) {
      short8 af[4], bf[4];
#pragma unroll
      for (int mt = 0; mt < 4; ++mt)
        af[mt] = *reinterpret_cast<const short8*>(
            ldsA + (wm * 64 + mt * 16 + r) * 64 + kk + kg);
#pragma unroll
      for (int nt = 0; nt < 4; ++nt)
        bf[nt] = *reinterpret_cast<const short8*>(
            ldsB + (wn * 64 + nt * 16 + r) * 64 + kk + kg);
#pragma unroll
      for (int mt = 0; mt < 4; ++mt)
#pragma unroll
        for (int nt = 0; nt < 4; ++nt)
          acc[mt][nt] = __builtin_amdgcn_mfma_f32_16x16x32_bf16(
              af[mt], bf[nt], acc[mt][nt], 0, 0, 0);
    }
    __syncthreads();
  }
}

// ---------------------------------------------------------------------------
// Q/K/V projection GEMM. grid (D/128, S/128, 3B), block 256.
// Q/K head-blocked [b][h][s][64]; Q pre-scaled by 0.125*log2(e) (exp2-domain
// softmax downstream). V -> [b][h][d][s].
// ---------------------------------------------------------------------------
__global__ __launch_bounds__(256) void k_proj_gemm(
    const short* __restrict__ xbf, const short* __restrict__ pbf,
    const short* __restrict__ WqT, const short* __restrict__ WkT,
    const short* __restrict__ WvT,
    const float* __restrict__ bq, const float* __restrict__ bk,
    const float* __restrict__ bv,
    const int* __restrict__ mask,
    short* __restrict__ Qhb, short* __restrict__ Khb, short* __restrict__ VT) {
  int b = blockIdx.z / 3, p = blockIdx.z % 3;
  if (mask[b] == 0) return;
  __shared__ short ldsA[128 * 64], ldsB[128 * 64];
  const short* A = (p == 0 ? xbf : pbf) + (size_t)b * S * D;
  const short* WT = p == 0 ? WqT : (p == 1 ? WkT : WvT);
  const float* bias = p == 0 ? bq : (p == 1 ? bk : bv);
  int m0 = blockIdx.y * 128, n0 = blockIdx.x * 128;
  f32x4 acc[4][4] = {};
  gemm_mainloop(A, WT, m0, n0, ldsA, ldsB, acc);

  int wave = threadIdx.x >> 6, lane = threadIdx.x & 63;
  int wm = wave >> 1, wn = wave & 1, r = lane & 15;
  int rbase0 = m0 + wm * 64 + (lane >> 4) * 4;
  if (p < 2) {
    short* O = p == 0 ? Qhb : Khb;
    float scale = p == 0 ? 0.18033688f : 1.0f;  // 0.125 * log2(e) for Q
#pragma unroll
    for (int mt = 0; mt < 4; ++mt) {
      int rbase = rbase0 + mt * 16;
#pragma unroll
      for (int nt = 0; nt < 4; ++nt) {
        int col = n0 + wn * 64 + nt * 16 + r;
        float bb = bias[col];
        int h = col >> 6, d = col & 63;
#pragma unroll
        for (int j = 0; j < 4; ++j)
          O[((size_t)(b * H + h) * S + rbase + j) * DH + d] =
              f2bf((acc[mt][nt][j] + bb) * scale);
      }
    }
  } else {
#pragma unroll
    for (int mt = 0; mt < 4; ++mt) {
      int rbase = rbase0 + mt * 16;
#pragma unroll
      for (int nt = 0; nt < 4; ++nt) {
        int col = n0 + wn * 64 + nt * 16 + r;
        float bb = bias[col];
        int h = col >> 6, d = col & 63;
        unsigned w0 = pkrn(acc[mt][nt][0] + bb, acc[mt][nt][1] + bb);
        unsigned w1 = pkrn(acc[mt][nt][2] + bb, acc[mt][nt][3] + bb);
        *reinterpret_cast<uint2v*>(
            VT + ((size_t)((b * H + h) * DH + d)) * S + rbase) =
            (uint2v){w0, w1};
      }
    }
  }
}

// ---------------------------------------------------------------------------
// Output projection + bias + residual (active) / copy (inactive).
// ---------------------------------------------------------------------------
__global__ __launch_bounds__(256) void k_out_gemm(
    const float* __restrict__ x, const short* __restrict__ attn,
    const short* __restrict__ WoT, const float* __restrict__ bo,
    const int* __restrict__ mask, float* __restrict__ out) {
  int b = blockIdx.z;
  int m0 = blockIdx.y * 128, n0 = blockIdx.x * 128;
  if (mask[b] == 0) {
#pragma unroll
    for (int i = 0; i < 16; ++i) {
      int f = threadIdx.x + i * 256;
      int row = f >> 5, cc = (f & 31) << 2;
      size_t idx = ((size_t)(b * S + m0 + row)) * D + n0 + cc;
      *reinterpret_cast<float4*>(out + idx) =
          *reinterpret_cast<const float4*>(x + idx);
    }
    return;
  }
  __shared__ short ldsA[128 * 64], ldsB[128 * 64];
  const short* A = attn + (size_t)b * S * D;
  f32x4 acc[4][4] = {};
  gemm_mainloop(A, WoT, m0, n0, ldsA, ldsB, acc);

  int wave = threadIdx.x >> 6, lane = threadIdx.x & 63;
  int wm = wave >> 1, wn = wave & 1, r = lane & 15;
  int rbase0 = m0 + wm * 64 + (lane >> 4) * 4;
#pragma unroll
  for (int mt = 0; mt < 4; ++mt) {
    int rbase = rbase0 + mt * 16;
#pragma unroll
    for (int nt = 0; nt < 4; ++nt) {
      int col = n0 + wn * 64 + nt * 16 + r;
      float bb = bo[col];
#pragma unroll
      for (int j = 0; j < 4; ++j) {
        size_t idx = (size_t)(b * S + rbase + j) * D + col;
        out[idx] = x[idx] + acc[mt][nt][j] + bb;
      }
    }
  }
}

// ---------------------------------------------------------------------------
// Flash attention, swapped-QK^T 32x32, in-register exp2-domain softmax,
// in-block kv-split. grid (S/32, H, B), block 256. Waves share one 32-row
// q-tile; wave w owns kv rows [w*512,(w+1)*512). Partials merged in LDS.
// Cross-lane via __shfl_xor(.,32) (R4-proven).
// ---------------------------------------------------------------------------
__global__ __launch_bounds__(256) void k_attn(
    const short* __restrict__ Qhb, const short* __restrict__ Khb,
    const short* __restrict__ VT,
    const int* __restrict__ mask, short* __restrict__ attn) {
  int b = blockIdx.z;
  if (mask[b] == 0) return;
  int h = blockIdx.y;
  int wave = threadIdx.x >> 6, lane = threadIdx.x & 63;
  int lr = lane & 31, hi = lane >> 5;
  int q0 = blockIdx.x * 32;
  // slope in log2 domain: slope * log2(e)
  float slope2 = exp2f(-0.5f * (float)(h + 1)) * 1.44269504f;

  const short* Qb = Qhb + (size_t)(b * H + h) * S * DH;
  const short* Kb = Khb + (size_t)(b * H + h) * S * DH;
  const short* Vb = VT + (size_t)(b * H + h) * DH * S;

  __shared__ alignas(16) short po[KVS][32][68];  // bf16 partial O, padded
  __shared__ float mlm[KVS][32], mll[KVS][32];

  // hoist Q B-fragments (col = q = lane&31, depth d = ds*16 + hi*8 + j)
  short8 qf[4];
  const short* qp = Qb + (size_t)(q0 + lr) * DH + hi * 8;
#pragma unroll
  for (int ds = 0; ds < 4; ++ds)
    qf[ds] = *reinterpret_cast<const short8*>(qp + ds * 16);

  f32x16 o0 = {}, o1 = {};
  float m = -INFINITY, l = 0.f;
  int kv_begin = wave * (S / KVS), kv_end = kv_begin + S / KVS;
  float dbase = (float)(kv_begin + 4 * hi - (q0 + lr));

  for (int kv0 = kv_begin; kv0 < kv_end; kv0 += 32) {
    // ---- QK^T swapped: C[k'][q], 4 MFMA over DH=64 (Q pre-scaled)
    const short* kp = Kb + (size_t)(kv0 + lr) * DH + hi * 8;
    f32x16 c = {};
#pragma unroll
    for (int ds = 0; ds < 4; ++ds)
      c = __builtin_amdgcn_mfma_f32_32x32x16_bf16(
          *reinterpret_cast<const short8*>(kp + ds * 16), qf[ds], c, 0, 0, 0);

    // ---- hoist V-tile loads (P-independent) above the softmax chain
    const short* vp = Vb + (size_t)lr * S + kv0 + hi * 8;
    short8 va0 = *reinterpret_cast<const short8*>(vp);
    short8 va1 = *reinterpret_cast<const short8*>(vp + 16);
    short8 vb0 = *reinterpret_cast<const short8*>(vp + (size_t)32 * S);
    short8 vb1 = *reinterpret_cast<const short8*>(vp + (size_t)32 * S + 16);

    // ---- alibi bias in log2 domain (abs = free input modifier)
    float p[16];
#pragma unroll
    for (int r2 = 0; r2 < 16; ++r2) {
      float dd = dbase + (float)((r2 & 3) + 8 * (r2 >> 2));
      p[r2] = __builtin_fmaf(-slope2, __builtin_fabsf(dd), c[r2]);
    }
    dbase += 32.f;

    // ---- tile max (max3-friendly tree) + cross-half merge
    float tmax = fmaxf(
        max3f(max3f(p[0], p[1], p[2]), max3f(p[3], p[4], p[5]),
              max3f(p[6], p[7], p[8])),
        max3f(max3f(p[9], p[10], p[11]), max3f(p[12], p[13], p[14]), p[15]));
    tmax = fmaxf(tmax, __shfl_xor(tmax, 32));

    // ---- online softmax with defer-max (THR = 8 nats = 11.5 log2-units)
    if (!__all(tmax <= m + 11.5f)) {
      float mn = fmaxf(m, tmax);
      float fac = __builtin_exp2f(m - mn);
      m = mn;
      l *= fac;
#pragma unroll
      for (int r2 = 0; r2 < 16; ++r2) { o0[r2] *= fac; o1[r2] *= fac; }
    }
#pragma unroll
    for (int r2 = 0; r2 < 16; ++r2) p[r2] = __builtin_exp2f(p[r2] - m);
    float s0a = (p[0] + p[1]) + (p[2] + p[3]);
    float s0b = (p[4] + p[5]) + (p[6] + p[7]);
    float s1a = (p[8] + p[9]) + (p[10] + p[11]);
    float s1b = (p[12] + p[13]) + (p[14] + p[15]);
    float ssum = (s0a + s0b) + (s1a + s1b);
    ssum += __shfl_xor(ssum, 32);
    l += ssum;

    // ---- pack P -> PV B-fragments (R4-proven shfl_xor exchange)
    unsigned c0 = pkrn(p[0], p[1]), c1 = pkrn(p[2], p[3]);
    unsigned c2 = pkrn(p[4], p[5]), c3 = pkrn(p[6], p[7]);
    unsigned c4 = pkrn(p[8], p[9]), c5 = pkrn(p[10], p[11]);
    unsigned c6 = pkrn(p[12], p[13]), c7 = pkrn(p[14], p[15]);
    unsigned s0 = (unsigned)__shfl_xor((int)(hi ? c0 : c2), 32);
    unsigned s1 = (unsigned)__shfl_xor((int)(hi ? c1 : c3), 32);
    unsigned s2 = (unsigned)__shfl_xor((int)(hi ? c4 : c6), 32);
    unsigned s3 = (unsigned)__shfl_xor((int)(hi ? c5 : c7), 32);
    U8 pb0, pb1;
    pb0.u[0] = hi ? s0 : c0; pb0.u[1] = hi ? s1 : c1;
    pb0.u[2] = hi ? c2 : s0; pb0.u[3] = hi ? c3 : s1;
    pb1.u[0] = hi ? s2 : c4; pb1.u[1] = hi ? s3 : c5;
    pb1.u[2] = hi ? c6 : s2; pb1.u[3] = hi ? c7 : s3;

    // ---- PV: OT[dv][q] += V^T-tile @ P
    o0 = __builtin_amdgcn_mfma_f32_32x32x16_bf16(va0, pb0.s, o0, 0, 0, 0);
    o1 = __builtin_amdgcn_mfma_f32_32x32x16_bf16(vb0, pb0.s, o1, 0, 0, 0);
    o0 = __builtin_amdgcn_mfma_f32_32x32x16_bf16(va1, pb1.s, o0, 0, 0, 0);
    o1 = __builtin_amdgcn_mfma_f32_32x32x16_bf16(vb1, pb1.s, o1, 0, 0, 0);
  }

  // ---- write per-wave partials (dv = 8g + 4hi + j; o1 -> dv+32)
#pragma unroll
  for (int g = 0; g < 4; ++g) {
    unsigned w0 = pkrn(o0[g * 4 + 0], o0[g * 4 + 1]);
    unsigned w1 = pkrn(o0[g * 4 + 2], o0[g * 4 + 3]);
    unsigned w2 = pkrn(o1[g * 4 + 0], o1[g * 4 + 1]);
    unsigned w3 = pkrn(o1[g * 4 + 2], o1[g * 4 + 3]);
    *reinterpret_cast<uint2v*>(&po[wave][lr][8 * g + 4 * hi]) = (uint2v){w0, w1};
    *reinterpret_cast<uint2v*>(&po[wave][lr][32 + 8 * g + 4 * hi]) =
        (uint2v){w2, w3};
  }
  if (hi == 0) { mlm[wave][lr] = m; mll[wave][lr] = l; }
  __syncthreads();

  // ---- flash combine across the 4 kv-split waves
  int qr = threadIdx.x & 31, cc = threadIdx.x >> 5;  // cc = dv chunk (0..7)
  float mw[KVS], M = -INFINITY;
#pragma unroll
  for (int w = 0; w < KVS; ++w) { mw[w] = mlm[w][qr]; M = fmaxf(M, mw[w]); }
  float L = 0.f, O[8] = {};
#pragma unroll
  for (int w = 0; w < KVS; ++w) {
    float sc = __builtin_exp2f(mw[w] - M);
    L += sc * mll[w][qr];
    short4v a = *reinterpret_cast<const short4v*>(&po[w][qr][cc * 8]);
    short4v b2 = *reinterpret_cast<const short4v*>(&po[w][qr][cc * 8 + 4]);
#pragma unroll
    for (int j = 0; j < 4; ++j) {
      O[j] += sc * bf2f(a[j]);
      O[4 + j] += sc * bf2f(b2[j]);
    }
  }
  float invL = 1.0f / L;
  U8 r8;
  r8.u[0] = pkrn(O[0] * invL, O[1] * invL);
  r8.u[1] = pkrn(O[2] * invL, O[3] * invL);
  r8.u[2] = pkrn(O[4] * invL, O[5] * invL);
  r8.u[3] = pkrn(O[6] * invL, O[7] * invL);
  *reinterpret_cast<short8*>(
      attn + (size_t)(b * S + q0 + qr) * D + h * DH + cc * 8) = r8.s;
}

}  // namespace

extern "C" void kernel_launch(void* const* d_in, const int* in_sizes, int n_in,
                              void* d_out, int out_size, void* d_ws, size_t ws_size,
                              hipStream_t stream) {
  const float* x    = (const float*)d_in[0];
  const float* prev = (const float*)d_in[1];
  const float* Wq   = (const float*)d_in[2];
  const float* Wk   = (const float*)d_in[3];
  const float* Wv   = (const float*)d_in[4];
  const float* Wo   = (const float*)d_in[5];
  const float* bq   = (const float*)d_in[6];
  const float* bk   = (const float*)d_in[7];
  const float* bv   = (const float*)d_in[8];
  const float* bo   = (const float*)d_in[9];
  const int* mask   = (const int*)d_in[10];
  float* out = (float*)d_out;
  char* ws = (char*)d_ws;

  constexpr size_t WSZ = (size_t)D * D * 2;      // 2 MB per bf16 weight
  constexpr size_t ASZ = (size_t)B * S * D * 2;  // 16 MB per bf16 activation
  short* WqT  = (short*)(ws);
  short* WkT  = (short*)(ws + WSZ);
  short* WvT  = (short*)(ws + 2 * WSZ);
  short* WoT  = (short*)(ws + 3 * WSZ);
  short* Qhb  = (short*)(ws + 4 * WSZ);
  short* Khb  = (short*)(ws + 4 * WSZ + ASZ);
  short* VT   = (short*)(ws + 4 * WSZ + 2 * ASZ);
  short* xbf  = (short*)(ws + 4 * WSZ + 3 * ASZ);  // attn aliases xbf (dead after proj)
  short* pbf  = (short*)(ws + 4 * WSZ + 4 * ASZ);
  short* attn = xbf;

  k_transpose<<<dim3(D / 32, D / 32, 4), dim3(32, 8), 0, stream>>>(
      Wq, Wk, Wv, Wo, WqT, WkT, WvT, WoT);
  k_cvt<<<dim3(S * D / 2048, 2, B), 256, 0, stream>>>(x, prev, mask, xbf, pbf);
  k_proj_gemm<<<dim3(D / 128, S / 128, 3 * B), 256, 0, stream>>>(
      xbf, pbf, WqT, WkT, WvT, bq, bk, bv, mask, Qhb, Khb, VT);
  k_attn<<<dim3(S / 32, H, B), 256, 0, stream>>>(Qhb, Khb, VT, mask, attn);
  k_out_gemm<<<dim3(D / 128, S / 128, B), 256, 0, stream>>>(
      x, attn, WoT, bo, mask, out);
}

// Round 7
// 222.798 us; speedup vs baseline: 1.0052x; 1.0052x over previous
//
#include <hip/hip_runtime.h>
#include <hip/hip_bf16.h>

namespace {

constexpr int B = 4, S = 2048, D = 1024, H = 16, DH = 64;

typedef __attribute__((ext_vector_type(8))) short short8;
typedef __attribute__((ext_vector_type(4))) short short4v;
typedef __attribute__((ext_vector_type(2))) unsigned uint2v;
typedef __attribute__((ext_vector_type(4))) float f32x4;
typedef __attribute__((ext_vector_type(16))) float f32x16;

union U8 { unsigned u[4]; short8 s; };
union BF2 { __hip_bfloat162 h; unsigned u; };

__device__ __forceinline__ short f2bf(float f) {
  unsigned u = __builtin_bit_cast(unsigned, f);
  u = (u + 0x7fffu + ((u >> 16) & 1u)) >> 16;
  return (short)u;
}

// packed f32x2 -> bf16x2 via HIP intrinsic (compiler emits v_cvt_pk_bf16_f32)
__device__ __forceinline__ unsigned pkrn(float a, float b) {
  BF2 r;
  r.h = __float22bfloat162_rn(float2{a, b});
  return r.u;
}

__device__ __forceinline__ float max3f(float a, float b, float c) {
  return fmaxf(fmaxf(a, b), c);
}

__device__ __forceinline__ short8 cvt8(const float* p) {
  float4 a = *reinterpret_cast<const float4*>(p);
  float4 b2 = *reinterpret_cast<const float4*>(p + 4);
  short8 r;
  r[0] = f2bf(a.x); r[1] = f2bf(a.y); r[2] = f2bf(a.z); r[3] = f2bf(a.w);
  r[4] = f2bf(b2.x); r[5] = f2bf(b2.y); r[6] = f2bf(b2.z); r[7] = f2bf(b2.w);
  return r;
}

__device__ __forceinline__ void gl_lds16(const void* g, void* l) {
  __builtin_amdgcn_global_load_lds(
      (const __attribute__((address_space(1))) void*)g,
      (__attribute__((address_space(3))) void*)l, 16, 0, 0);
}

// ---------------------------------------------------------------------------
// Transpose + bf16-convert the 4 weight matrices: WT[n][k] = bf16(W[k][n]).
// ---------------------------------------------------------------------------
__global__ __launch_bounds__(256) void k_transpose(
    const float* __restrict__ Wq, const float* __restrict__ Wk,
    const float* __restrict__ Wv, const float* __restrict__ Wo,
    short* __restrict__ WqT, short* __restrict__ WkT,
    short* __restrict__ WvT, short* __restrict__ WoT) {
  __shared__ float tile[32][33];
  int z = blockIdx.z;
  const float* W = z == 0 ? Wq : z == 1 ? Wk : z == 2 ? Wv : Wo;
  short* WT = z == 0 ? WqT : z == 1 ? WkT : z == 2 ? WvT : WoT;
  int n0 = blockIdx.x * 32, k0 = blockIdx.y * 32;
  int tx = threadIdx.x, ty = threadIdx.y;
#pragma unroll
  for (int i = 0; i < 4; ++i) {
    int r = i * 8 + ty;
    tile[r][tx] = W[(size_t)(k0 + r) * D + n0 + tx];
  }
  __syncthreads();
#pragma unroll
  for (int i = 0; i < 4; ++i) {
    int r = i * 8 + ty;
    WT[(size_t)(n0 + r) * D + k0 + tx] = f2bf(tile[tx][r]);
  }
}

// ---------------------------------------------------------------------------
// Convert x / prev rows of active batches to bf16 (grid: (S*D/2048, 2, B))
// ---------------------------------------------------------------------------
__global__ __launch_bounds__(256) void k_cvt(
    const float* __restrict__ x, const float* __restrict__ prev,
    const int* __restrict__ mask,
    short* __restrict__ xbf, short* __restrict__ pbf) {
  int b = blockIdx.z;
  if (mask[b] == 0) return;
  const float* src = (blockIdx.y ? prev : x) + (size_t)b * S * D;
  short* dst = (blockIdx.y ? pbf : xbf) + (size_t)b * S * D;
  size_t i = ((size_t)blockIdx.x * 256 + threadIdx.x) * 8;
  *reinterpret_cast<short8*>(dst + i) = cvt8(src + i);
}

// ---------------------------------------------------------------------------
// Shared GEMM mainloop (m97 structure): C[128x128] = A[128xK] @ B^T.
// ---------------------------------------------------------------------------
__device__ __forceinline__ void stage128x64(const short* __restrict__ src,
                                            short* lds, int wave, int lane) {
#pragma unroll
  for (int c = 0; c < 4; ++c) {
    int r0 = wave * 32 + c * 8;
    gl_lds16(src + (size_t)(r0 + (lane >> 3)) * D + (lane & 7) * 8,
             lds + r0 * 64);
  }
}

__device__ __forceinline__ void gemm_mainloop(
    const short* __restrict__ A, const short* __restrict__ Bm,
    int m0, int n0, short* ldsA, short* ldsB, f32x4 acc[4][4]) {
  int wave = threadIdx.x >> 6, lane = threadIdx.x & 63;
  int wm = wave >> 1, wn = wave & 1;
  int kg = (lane >> 4) * 8, r = lane & 15;
  const short* Ab = A + (size_t)m0 * D;
  const short* Bb = Bm + (size_t)n0 * D;
  for (int kt = 0; kt < D; kt += 64) {
    stage128x64(Ab + kt, ldsA, wave, lane);
    stage128x64(Bb + kt, ldsB, wave, lane);
    __syncthreads();
#pragma unroll
    for (int kk = 0; kk < 64; kk += 32) {
      short8 af[4], bf[4];
#pragma unroll
      for (int mt = 0; mt < 4; ++mt)
        af[mt] = *reinterpret_cast<const short8*>(
            ldsA + (wm * 64 + mt * 16 + r) * 64 + kk + kg);
#pragma unroll
      for (int nt = 0; nt < 4; ++nt)
        bf[nt] = *reinterpret_cast<const short8*>(
            ldsB + (wn * 64 + nt * 16 + r) * 64 + kk + kg);
#pragma unroll
      for (int mt = 0; mt < 4; ++mt)
#pragma unroll
        for (int nt = 0; nt < 4; ++nt)
          acc[mt][nt] = __builtin_amdgcn_mfma_f32_16x16x32_bf16(
              af[mt], bf[nt], acc[mt][nt], 0, 0, 0);
    }
    __syncthreads();
  }
}

// ---------------------------------------------------------------------------
// Q/K/V projection GEMM. grid (D/128, S/128, 3B), block 256.
// Q/K head-blocked [b][h][s][64]; Q pre-scaled by 0.125*log2(e) (exp2-domain
// softmax downstream). V -> [b][h][d][s].
// ---------------------------------------------------------------------------
__global__ __launch_bounds__(256) void k_proj_gemm(
    const short* __restrict__ xbf, const short* __restrict__ pbf,
    const short* __restrict__ WqT, const short* __restrict__ WkT,
    const short* __restrict__ WvT,
    const float* __restrict__ bq, const float* __restrict__ bk,
    const float* __restrict__ bv,
    const int* __restrict__ mask,
    short* __restrict__ Qhb, short* __restrict__ Khb, short* __restrict__ VT) {
  int b = blockIdx.z / 3, p = blockIdx.z % 3;
  if (mask[b] == 0) return;
  __shared__ short ldsA[128 * 64], ldsB[128 * 64];
  const short* A = (p == 0 ? xbf : pbf) + (size_t)b * S * D;
  const short* WT = p == 0 ? WqT : (p == 1 ? WkT : WvT);
  const float* bias = p == 0 ? bq : (p == 1 ? bk : bv);
  int m0 = blockIdx.y * 128, n0 = blockIdx.x * 128;
  f32x4 acc[4][4] = {};
  gemm_mainloop(A, WT, m0, n0, ldsA, ldsB, acc);

  int wave = threadIdx.x >> 6, lane = threadIdx.x & 63;
  int wm = wave >> 1, wn = wave & 1, r = lane & 15;
  int rbase0 = m0 + wm * 64 + (lane >> 4) * 4;
  if (p < 2) {
    short* O = p == 0 ? Qhb : Khb;
    float scale = p == 0 ? 0.18033688f : 1.0f;  // 0.125 * log2(e) for Q
#pragma unroll
    for (int mt = 0; mt < 4; ++mt) {
      int rbase = rbase0 + mt * 16;
#pragma unroll
      for (int nt = 0; nt < 4; ++nt) {
        int col = n0 + wn * 64 + nt * 16 + r;
        float bb = bias[col];
        int h = col >> 6, d = col & 63;
#pragma unroll
        for (int j = 0; j < 4; ++j)
          O[((size_t)(b * H + h) * S + rbase + j) * DH + d] =
              f2bf((acc[mt][nt][j] + bb) * scale);
      }
    }
  } else {
#pragma unroll
    for (int mt = 0; mt < 4; ++mt) {
      int rbase = rbase0 + mt * 16;
#pragma unroll
      for (int nt = 0; nt < 4; ++nt) {
        int col = n0 + wn * 64 + nt * 16 + r;
        float bb = bias[col];
        int h = col >> 6, d = col & 63;
        unsigned w0 = pkrn(acc[mt][nt][0] + bb, acc[mt][nt][1] + bb);
        unsigned w1 = pkrn(acc[mt][nt][2] + bb, acc[mt][nt][3] + bb);
        *reinterpret_cast<uint2v*>(
            VT + ((size_t)((b * H + h) * DH + d)) * S + rbase) =
            (uint2v){w0, w1};
      }
    }
  }
}

// ---------------------------------------------------------------------------
// Output projection + bias + residual (active) / copy (inactive).
// ---------------------------------------------------------------------------
__global__ __launch_bounds__(256) void k_out_gemm(
    const float* __restrict__ x, const short* __restrict__ attn,
    const short* __restrict__ WoT, const float* __restrict__ bo,
    const int* __restrict__ mask, float* __restrict__ out) {
  int b = blockIdx.z;
  int m0 = blockIdx.y * 128, n0 = blockIdx.x * 128;
  if (mask[b] == 0) {
#pragma unroll
    for (int i = 0; i < 16; ++i) {
      int f = threadIdx.x + i * 256;
      int row = f >> 5, cc = (f & 31) << 2;
      size_t idx = ((size_t)(b * S + m0 + row)) * D + n0 + cc;
      *reinterpret_cast<float4*>(out + idx) =
          *reinterpret_cast<const float4*>(x + idx);
    }
    return;
  }
  __shared__ short ldsA[128 * 64], ldsB[128 * 64];
  const short* A = attn + (size_t)b * S * D;
  f32x4 acc[4][4] = {};
  gemm_mainloop(A, WoT, m0, n0, ldsA, ldsB, acc);

  int wave = threadIdx.x >> 6, lane = threadIdx.x & 63;
  int wm = wave >> 1, wn = wave & 1, r = lane & 15;
  int rbase0 = m0 + wm * 64 + (lane >> 4) * 4;
#pragma unroll
  for (int mt = 0; mt < 4; ++mt) {
    int rbase = rbase0 + mt * 16;
#pragma unroll
    for (int nt = 0; nt < 4; ++nt) {
      int col = n0 + wn * 64 + nt * 16 + r;
      float bb = bo[col];
#pragma unroll
      for (int j = 0; j < 4; ++j) {
        size_t idx = (size_t)(b * S + rbase + j) * D + col;
        out[idx] = x[idx] + acc[mt][nt][j] + bb;
      }
    }
  }
}

// ---------------------------------------------------------------------------
// Flash attention, swapped-QK^T 32x32, in-register exp2-domain softmax.
// grid (S/128, H, B), block 256: 4 waves, each owns 32 q-rows of a shared
// 128-row q-tile and sweeps the FULL kv range (shared K/V tiles -> L1/L2
// reuse across waves; 4x less L2/L3 traffic than kv-split).
// K register-double-buffered: K(t+1) loads issue before tile t's softmax/PV
// chain so load latency hides under compute. No LDS.
// ---------------------------------------------------------------------------
__global__ __launch_bounds__(256) void k_attn(
    const short* __restrict__ Qhb, const short* __restrict__ Khb,
    const short* __restrict__ VT,
    const int* __restrict__ mask, short* __restrict__ attn) {
  int b = blockIdx.z;
  if (mask[b] == 0) return;
  int h = blockIdx.y;
  int wave = threadIdx.x >> 6, lane = threadIdx.x & 63;
  int lr = lane & 31, hi = lane >> 5;
  int q0w = blockIdx.x * 128 + wave * 32;
  // slope in log2 domain: slope * log2(e)
  float slope2 = exp2f(-0.5f * (float)(h + 1)) * 1.44269504f;

  const short* Qb = Qhb + (size_t)(b * H + h) * S * DH;
  const short* Kb = Khb + (size_t)(b * H + h) * S * DH;
  const short* Vb = VT + (size_t)(b * H + h) * DH * S;

  // hoist Q B-fragments (col = q = lane&31, depth d = ds*16 + hi*8 + j)
  short8 qf[4];
  const short* qp = Qb + (size_t)(q0w + lr) * DH + hi * 8;
#pragma unroll
  for (int ds = 0; ds < 4; ++ds)
    qf[ds] = *reinterpret_cast<const short8*>(qp + ds * 16);

  f32x16 o0 = {}, o1 = {};
  float m = -INFINITY, l = 0.f;
  float dbase = (float)(4 * hi - (q0w + lr));

  short8 ka[4], kb2[4];
  // preload K tile 0
  {
    const short* kp = Kb + (size_t)lr * DH + hi * 8;
#pragma unroll
    for (int ds = 0; ds < 4; ++ds)
      ka[ds] = *reinterpret_cast<const short8*>(kp + ds * 16);
  }

#define ATTN_TILE(KF, KNXT, KV0)                                               \
  {                                                                            \
    /* prefetch next K tile into KNXT (wraps at S; harmless extra load) */     \
    const short* kp =                                                          \
        Kb + (size_t)((((KV0) + 32) & (S - 1)) + lr) * DH + hi * 8;            \
    _Pragma("unroll") for (int ds = 0; ds < 4; ++ds)                           \
        KNXT[ds] = *reinterpret_cast<const short8*>(kp + ds * 16);             \
    /* V tile loads (consumed at PV, ~350 cyc below) */                        \
    const short* vp = Vb + (size_t)lr * S + (KV0) + hi * 8;                    \
    short8 va0 = *reinterpret_cast<const short8*>(vp);                         \
    short8 va1 = *reinterpret_cast<const short8*>(vp + 16);                    \
    short8 vb0 = *reinterpret_cast<const short8*>(vp + (size_t)32 * S);        \
    short8 vb1 = *reinterpret_cast<const short8*>(vp + (size_t)32 * S + 16);   \
    /* QK^T swapped: C[k'][q], 4 MFMA over DH=64 (Q pre-scaled) */             \
    f32x16 c = {};                                                             \
    _Pragma("unroll") for (int ds = 0; ds < 4; ++ds)                           \
        c = __builtin_amdgcn_mfma_f32_32x32x16_bf16(KF[ds], qf[ds], c, 0, 0,   \
                                                    0);                        \
    /* alibi bias in log2 domain (abs = free input modifier) */                \
    _Pragma("unroll") for (int r2 = 0; r2 < 16; ++r2) {                        \
      float dd = dbase + (float)((r2 & 3) + 8 * (r2 >> 2));                    \
      c[r2] = __builtin_fmaf(-slope2, __builtin_fabsf(dd), c[r2]);             \
    }                                                                          \
    dbase += 32.f;                                                             \
    float tmax = fmaxf(                                                        \
        max3f(max3f(c[0], c[1], c[2]), max3f(c[3], c[4], c[5]),                \
              max3f(c[6], c[7], c[8])),                                        \
        max3f(max3f(c[9], c[10], c[11]), max3f(c[12], c[13], c[14]), c[15])); \
    tmax = fmaxf(tmax, __shfl_xor(tmax, 32));                                  \
    if (!__all(tmax <= m + 11.5f)) {                                           \
      float mn = fmaxf(m, tmax);                                               \
      float fac = __builtin_exp2f(m - mn);                                     \
      m = mn;                                                                  \
      l *= fac;                                                                \
      _Pragma("unroll") for (int r2 = 0; r2 < 16; ++r2) {                      \
        o0[r2] *= fac;                                                         \
        o1[r2] *= fac;                                                         \
      }                                                                        \
    }                                                                          \
    _Pragma("unroll") for (int r2 = 0; r2 < 16; ++r2)                          \
        c[r2] = __builtin_exp2f(c[r2] - m);                                    \
    float s0a = (c[0] + c[1]) + (c[2] + c[3]);                                 \
    float s0b = (c[4] + c[5]) + (c[6] + c[7]);                                 \
    float s1a = (c[8] + c[9]) + (c[10] + c[11]);                               \
    float s1b = (c[12] + c[13]) + (c[14] + c[15]);                             \
    float ssum = (s0a + s0b) + (s1a + s1b);                                    \
    ssum += __shfl_xor(ssum, 32);                                              \
    l += ssum;                                                                 \
    /* pack P -> PV B-fragments */                                             \
    unsigned c0 = pkrn(c[0], c[1]), c1 = pkrn(c[2], c[3]);                     \
    unsigned c2 = pkrn(c[4], c[5]), c3 = pkrn(c[6], c[7]);                     \
    unsigned c4 = pkrn(c[8], c[9]), c5 = pkrn(c[10], c[11]);                   \
    unsigned c6 = pkrn(c[12], c[13]), c7 = pkrn(c[14], c[15]);                 \
    unsigned s0 = (unsigned)__shfl_xor((int)(hi ? c0 : c2), 32);               \
    unsigned s1 = (unsigned)__shfl_xor((int)(hi ? c1 : c3), 32);               \
    unsigned s2 = (unsigned)__shfl_xor((int)(hi ? c4 : c6), 32);               \
    unsigned s3 = (unsigned)__shfl_xor((int)(hi ? c5 : c7), 32);               \
    U8 pb0, pb1;                                                               \
    pb0.u[0] = hi ? s0 : c0; pb0.u[1] = hi ? s1 : c1;                          \
    pb0.u[2] = hi ? c2 : s0; pb0.u[3] = hi ? c3 : s1;                          \
    pb1.u[0] = hi ? s2 : c4; pb1.u[1] = hi ? s3 : c5;                          \
    pb1.u[2] = hi ? c6 : s2; pb1.u[3] = hi ? c7 : s3;                          \
    /* PV: OT[dv][q] += V^T-tile @ P */                                        \
    o0 = __builtin_amdgcn_mfma_f32_32x32x16_bf16(va0, pb0.s, o0, 0, 0, 0);     \
    o1 = __builtin_amdgcn_mfma_f32_32x32x16_bf16(vb0, pb0.s, o1, 0, 0, 0);     \
    o0 = __builtin_amdgcn_mfma_f32_32x32x16_bf16(va1, pb1.s, o0, 0, 0, 0);     \
    o1 = __builtin_amdgcn_mfma_f32_32x32x16_bf16(vb1, pb1.s, o1, 0, 0, 0);     \
  }

  for (int kv0 = 0; kv0 < S; kv0 += 64) {
    ATTN_TILE(ka, kb2, kv0);
    ATTN_TILE(kb2, ka, kv0 + 32);
  }
#undef ATTN_TILE

  // ---- normalize + store (dv = 8g + 4hi + j; o1 -> dv+32)
  float invL = 1.0f / l;
  short* op = attn + (size_t)(b * S + q0w + lr) * D + h * DH;
#pragma unroll
  for (int g = 0; g < 4; ++g) {
    unsigned w0 = pkrn(o0[g * 4 + 0] * invL, o0[g * 4 + 1] * invL);
    unsigned w1 = pkrn(o0[g * 4 + 2] * invL, o0[g * 4 + 3] * invL);
    unsigned w2 = pkrn(o1[g * 4 + 0] * invL, o1[g * 4 + 1] * invL);
    unsigned w3 = pkrn(o1[g * 4 + 2] * invL, o1[g * 4 + 3] * invL);
    *reinterpret_cast<uint2v*>(op + 8 * g + 4 * hi) = (uint2v){w0, w1};
    *reinterpret_cast<uint2v*>(op + 32 + 8 * g + 4 * hi) = (uint2v){w2, w3};
  }
}

}  // namespace

extern "C" void kernel_launch(void* const* d_in, const int* in_sizes, int n_in,
                              void* d_out, int out_size, void* d_ws, size_t ws_size,
                              hipStream_t stream) {
  const float* x    = (const float*)d_in[0];
  const float* prev = (const float*)d_in[1];
  const float* Wq   = (const float*)d_in[2];
  const float* Wk   = (const float*)d_in[3];
  const float* Wv   = (const float*)d_in[4];
  const float* Wo   = (const float*)d_in[5];
  const float* bq   = (const float*)d_in[6];
  const float* bk   = (const float*)d_in[7];
  const float* bv   = (const float*)d_in[8];
  const float* bo   = (const float*)d_in[9];
  const int* mask   = (const int*)d_in[10];
  float* out = (float*)d_out;
  char* ws = (char*)d_ws;

  constexpr size_t WSZ = (size_t)D * D * 2;      // 2 MB per bf16 weight
  constexpr size_t ASZ = (size_t)B * S * D * 2;  // 16 MB per bf16 activation
  short* WqT  = (short*)(ws);
  short* WkT  = (short*)(ws + WSZ);
  short* WvT  = (short*)(ws + 2 * WSZ);
  short* WoT  = (short*)(ws + 3 * WSZ);
  short* Qhb  = (short*)(ws + 4 * WSZ);
  short* Khb  = (short*)(ws + 4 * WSZ + ASZ);
  short* VT   = (short*)(ws + 4 * WSZ + 2 * ASZ);
  short* xbf  = (short*)(ws + 4 * WSZ + 3 * ASZ);  // attn aliases xbf (dead after proj)
  short* pbf  = (short*)(ws + 4 * WSZ + 4 * ASZ);
  short* attn = xbf;

  k_transpose<<<dim3(D / 32, D / 32, 4), dim3(32, 8), 0, stream>>>(
      Wq, Wk, Wv, Wo, WqT, WkT, WvT, WoT);
  k_cvt<<<dim3(S * D / 2048, 2, B), 256, 0, stream>>>(x, prev, mask, xbf, pbf);
  k_proj_gemm<<<dim3(D / 128, S / 128, 3 * B), 256, 0, stream>>>(
      xbf, pbf, WqT, WkT, WvT, bq, bk, bv, mask, Qhb, Khb, VT);
  k_attn<<<dim3(S / 128, H, B), 256, 0, stream>>>(Qhb, Khb, VT, mask, attn);
  k_out_gemm<<<dim3(D / 128, S / 128, B), 256, 0, stream>>>(
      x, attn, WoT, bo, mask, out);
}